// Round 1
// baseline (7293.805 us; speedup 1.0000x reference)
//
#include <hip/hip_runtime.h>
#include <stdint.h>

#define NWG 256
#define NPHASE 259   // T + 3 pipeline stages

typedef __attribute__((ext_vector_type(8))) short short8;
typedef __attribute__((ext_vector_type(4))) float floatx4;

static constexpr int Bb = 128, Tt = 256, Dl = 256, Hs = 512, Hb = 1024;

// ---- workspace byte layout ----
static constexpr size_t OFF_CNT = 0;
static constexpr size_t OFF_B1  = 512;                                  // f32[2048]
static constexpr size_t OFF_B2  = OFF_B1 + 2048*4;                      // f32[2048]
static constexpr size_t OFF_B3  = OFF_B2 + 2048*4;                      // f32[4096]
static constexpr size_t OFF_BL  = OFF_B3 + 4096*4;                      // f32[256]
static constexpr size_t OFF_W1  = OFF_BL + 1024;                        // bf16[2048][768]
static constexpr size_t OFF_W2  = OFF_W1 + (size_t)2048*768*2;          // bf16[2048][1024]
static constexpr size_t OFF_W3  = OFF_W2 + (size_t)2048*1024*2;         // bf16[4096][1536]
static constexpr size_t OFF_WL  = OFF_W3 + (size_t)4096*1536*2;         // bf16[256][1024]
static constexpr size_t OFF_H1  = OFF_WL + (size_t)256*1024*2;          // bf16[4][128][512]
static constexpr size_t OFF_H2  = OFF_H1 + (size_t)4*128*512*2;
static constexpr size_t OFF_H3  = OFF_H2 + (size_t)4*128*512*2;         // bf16[4][128][1024]
static constexpr size_t WS_NEED = OFF_H3 + (size_t)4*128*1024*2;        // ~22.6 MB

__device__ __forceinline__ unsigned short f2bf(float f) {
  unsigned int u = __float_as_uint(f);
  unsigned int r = (u + 0x7fffu + ((u >> 16) & 1u)) >> 16;
  return (unsigned short)r;
}
__device__ __forceinline__ float sigm(float x) { return 1.f/(1.f + __expf(-x)); }
__device__ __forceinline__ float tanh_f(float x) {
  x = fminf(fmaxf(x, -15.f), 15.f);
  float e = __expf(-2.f*x);
  return (1.f - e)/(1.f + e);
}

// ---------------- init: weights->bf16 (concat [W_ih|W_hh]), bias sums, zero rings/counter ----------------
__global__ void lstm_init(
    const float* __restrict__ Wih1, const float* __restrict__ Whh1,
    const float* __restrict__ bih1, const float* __restrict__ bhh1,
    const float* __restrict__ Wih2, const float* __restrict__ Whh2,
    const float* __restrict__ bih2, const float* __restrict__ bhh2,
    const float* __restrict__ Wih3, const float* __restrict__ Whh3,
    const float* __restrict__ bih3, const float* __restrict__ bhh3,
    const float* __restrict__ Wlin, const float* __restrict__ blin,
    unsigned char* __restrict__ ws)
{
  size_t i0 = (size_t)blockIdx.x*blockDim.x + threadIdx.x;
  size_t np = (size_t)gridDim.x*blockDim.x;
  if (i0 == 0) *(unsigned int*)(ws + OFF_CNT) = 0u;

  float* b1 = (float*)(ws + OFF_B1);
  float* b2 = (float*)(ws + OFF_B2);
  float* b3 = (float*)(ws + OFF_B3);
  float* bl = (float*)(ws + OFF_BL);
  for (size_t i = i0; i < 2048; i += np) b1[i] = bih1[i] + bhh1[i];
  for (size_t i = i0; i < 2048; i += np) b2[i] = bih2[i] + bhh2[i];
  for (size_t i = i0; i < 4096; i += np) b3[i] = bih3[i] + bhh3[i];
  for (size_t i = i0; i < 256;  i += np) bl[i] = blin[i];

  unsigned short* w1 = (unsigned short*)(ws + OFF_W1);
  unsigned short* w2 = (unsigned short*)(ws + OFF_W2);
  unsigned short* w3 = (unsigned short*)(ws + OFF_W3);
  unsigned short* wl = (unsigned short*)(ws + OFF_WL);
  for (size_t i = i0; i < (size_t)2048*768; i += np) {
    size_t r = i/768, k = i - r*768;
    float v = (k < 256) ? Wih1[r*256 + k] : Whh1[r*512 + (k - 256)];
    w1[i] = f2bf(v);
  }
  for (size_t i = i0; i < (size_t)2048*1024; i += np) {
    size_t r = i >> 10, k = i & 1023;
    float v = (k < 512) ? Wih2[r*512 + k] : Whh2[r*512 + (k - 512)];
    w2[i] = f2bf(v);
  }
  for (size_t i = i0; i < (size_t)4096*1536; i += np) {
    size_t r = i/1536, k = i - r*1536;
    float v = (k < 512) ? Wih3[r*512 + k] : Whh3[r*1024 + (k - 512)];
    w3[i] = f2bf(v);
  }
  for (size_t i = i0; i < (size_t)256*1024; i += np) wl[i] = f2bf(Wlin[i]);

  unsigned short* rings = (unsigned short*)(ws + OFF_H1);
  for (size_t i = i0; i < (size_t)(4*128*512 + 4*128*512 + 4*128*1024); i += np) rings[i] = 0;
}

// ---------------- persistent pipelined LSTM kernel ----------------
// WG 0..63   : layer1, step t = p      (+ 16 of them also do the linear head, t = p-3)
// WG 64..127 : layer2, step t = p-1
// WG 128..255: layer3, step t = p-2
// Per WG: output block m64 x (16 units x 4 gates), waves = (m-split 2) x (K-split 2),
// LDS pair-reduce over K halves, inline cell update, c kept in registers.
__global__ void __launch_bounds__(256, 1)
lstm_persist(const float* __restrict__ X, float* __restrict__ out,
             unsigned char* __restrict__ ws)
{
  extern __shared__ unsigned char smem[];            // [0,131072): weight slice, [131072,+16K): reduce buf
  floatx4* red = (floatx4*)(smem + 131072);

  const int tid  = threadIdx.x;
  const int lane = tid & 63;
  const int wv   = tid >> 6;
  const int mi   = wv & 1;          // m-half within WG
  const int ki   = wv >> 1;         // K-half
  const int wg   = blockIdx.x;
  const int l15  = lane & 15;
  const int klo  = (lane >> 4) << 3;

  unsigned int* cnt = (unsigned int*)(ws + OFF_CNT);
  const float* bias1 = (const float*)(ws + OFF_B1);
  const float* bias2 = (const float*)(ws + OFF_B2);
  const float* bias3 = (const float*)(ws + OFF_B3);
  const float* biasl = (const float*)(ws + OFF_BL);
  const unsigned short* W1 = (const unsigned short*)(ws + OFF_W1);
  const unsigned short* W2 = (const unsigned short*)(ws + OFF_W2);
  const unsigned short* W3 = (const unsigned short*)(ws + OFF_W3);
  const unsigned short* WL = (const unsigned short*)(ws + OFF_WL);
  unsigned short* h1r = (unsigned short*)(ws + OFF_H1);
  unsigned short* h2r = (unsigned short*)(ws + OFF_H2);
  unsigned short* h3r = (unsigned short*)(ws + OFF_H3);

  int type, mbase, u0, H, Kfull, Kres;
  const unsigned short* Wg; const float* biasp;
  if (wg < 64)       { type = 0; int j = wg;       mbase = (j&1)*64; u0 = (j>>1)*16; Wg = W1; biasp = bias1; H = Hs; Kfull = 768;  Kres = 768;  }
  else if (wg < 128) { type = 1; int j = wg - 64;  mbase = (j&1)*64; u0 = (j>>1)*16; Wg = W2; biasp = bias2; H = Hs; Kfull = 1024; Kres = 1024; }
  else               { type = 2; int j = wg - 128; mbase = (j&1)*64; u0 = (j>>1)*16; Wg = W3; biasp = bias3; H = Hb; Kfull = 1536; Kres = 768;  }
  const int KresB = Kres*2;
  const int ksn   = (Kfull >> 1) >> 5;   // k-steps per wave

  const bool isOut = (wg < 64) && ((wg & 3) == 0);
  const int  ojob  = wg >> 2;            // 0..15
  const int  obase = (ojob & 1)*64;
  const int  osec  = (ojob >> 1)*32;

  // prologue: weight slice -> LDS, rows = 4 gates x 16 units, cols = Kres, XOR-swizzled
  {
    const int rowchunks = Kres >> 3;     // 16B chunks per row
    for (int idx = tid; idx < 64*rowchunks; idx += 256) {
      int r = idx / rowchunks, kc = idx - r*rowchunks;
      int R = (r >> 4)*H + u0 + (r & 15);
      uint4 v = *(const uint4*)(Wg + (size_t)R*Kfull + kc*8);
      int db = r*KresB + ((kc*16) ^ ((r & 7) << 4));
      *(uint4*)(smem + db) = v;
    }
  }
  float creg[8];
  #pragma unroll
  for (int i = 0; i < 8; ++i) creg[i] = 0.f;

  __syncthreads();

  for (int p = 0; p < NPHASE; ++p) {
    const int t = p - type;
    if (t >= 0 && t < Tt) {
      const unsigned short *segA, *segB;
      int kb1, pitchA, pitchB;
      if (type == 0)      { segA = h1r; pitchA = Hs; kb1 = 256;   // segA unused (x path)
                            segB = h1r + (size_t)((t-1)&3)*Bb*Hs; pitchB = Hs; }
      else if (type == 1) { segA = h1r + (size_t)(t&3)*Bb*Hs;     pitchA = Hs; kb1 = 512;
                            segB = h2r + (size_t)((t-1)&3)*Bb*Hs; pitchB = Hs; }
      else                { segA = h2r + (size_t)(t&3)*Bb*Hs;     pitchA = Hs; kb1 = 512;
                            segB = h3r + (size_t)((t-1)&3)*Bb*Hb; pitchB = Hb; }

      floatx4 acc[2][4];
      if (ki == 0) {
        #pragma unroll
        for (int g = 0; g < 4; ++g) {
          float bv = biasp[g*H + u0 + l15];
          floatx4 b4 = {bv, bv, bv, bv};
          acc[0][g] = b4; acc[1][g] = b4;
        }
      } else {
        floatx4 z = {0.f, 0.f, 0.f, 0.f};
        #pragma unroll
        for (int g = 0; g < 4; ++g) { acc[0][g] = z; acc[1][g] = z; }
      }

      const int ks0 = ki*ksn;
      for (int ks = 0; ks < ksn; ++ks) {
        const int k = (ks0 + ks) << 5;
        short8 a[2];
        #pragma unroll
        for (int mt = 0; mt < 2; ++mt) {
          const int row = mbase + mi*32 + mt*16 + l15;
          if (type == 0 && k < 256) {          // x_t, fp32 -> bf16 on the fly
            const float* xp = X + ((size_t)row*Tt + t)*Dl + (k + klo);
            float4 f0 = *(const float4*)xp;
            float4 f1 = *(const float4*)(xp + 4);
            short8 av;
            av[0] = (short)f2bf(f0.x); av[1] = (short)f2bf(f0.y);
            av[2] = (short)f2bf(f0.z); av[3] = (short)f2bf(f0.w);
            av[4] = (short)f2bf(f1.x); av[5] = (short)f2bf(f1.y);
            av[6] = (short)f2bf(f1.z); av[7] = (short)f2bf(f1.w);
            a[mt] = av;
          } else {
            const unsigned short* hp; int kk, pit;
            if (k < kb1) { hp = segA; kk = k;        pit = pitchA; }
            else         { hp = segB; kk = k - kb1;  pit = pitchB; }
            a[mt] = *(const short8*)(hp + (size_t)row*pit + kk + klo);
          }
        }
        short8 bf[4];
        const bool fromLds = (k < Kres);
        #pragma unroll
        for (int g = 0; g < 4; ++g) {
          if (fromLds) {
            int r  = (g << 4) + l15;
            int db = r*KresB + (((k + klo)*2) ^ ((r & 7) << 4));
            bf[g] = *(const short8*)(smem + db);
          } else {                              // layer-3 second K-half straight from L2
            int R = g*H + u0 + l15;
            bf[g] = *(const short8*)(Wg + (size_t)R*Kfull + k + klo);
          }
        }
        #pragma unroll
        for (int mt = 0; mt < 2; ++mt)
          #pragma unroll
          for (int g = 0; g < 4; ++g)
            acc[mt][g] = __builtin_amdgcn_mfma_f32_16x16x32_bf16(a[mt], bf[g], acc[mt][g], 0, 0, 0);
      }

      __syncthreads();
      if (ki == 1) {
        #pragma unroll
        for (int mt = 0; mt < 2; ++mt)
          #pragma unroll
          for (int g = 0; g < 4; ++g)
            red[(mi*8 + mt*4 + g)*64 + lane] = acc[mt][g];
      }
      __syncthreads();
      if (ki == 0) {
        unsigned short* hout = (type == 0 ? h1r : type == 1 ? h2r : h3r) + (size_t)(t&3)*Bb*H;
        #pragma unroll
        for (int mt = 0; mt < 2; ++mt) {
          floatx4 gi = acc[mt][0] + red[(mi*8 + mt*4 + 0)*64 + lane];
          floatx4 gf = acc[mt][1] + red[(mi*8 + mt*4 + 1)*64 + lane];
          floatx4 gg = acc[mt][2] + red[(mi*8 + mt*4 + 2)*64 + lane];
          floatx4 go = acc[mt][3] + red[(mi*8 + mt*4 + 3)*64 + lane];
          const int b0 = mbase + mi*32 + mt*16 + ((lane >> 4) << 2);
          const int u  = u0 + l15;
          #pragma unroll
          for (int j = 0; j < 4; ++j) {
            float iv = sigm(gi[j]);
            float fv = sigm(gf[j]);
            float gv = tanh_f(gg[j]);
            float ov = sigm(go[j]);
            float c  = fv*creg[mt*4 + j] + iv*gv;
            creg[mt*4 + j] = c;
            float h = ov*tanh_f(c);
            hout[(size_t)(b0 + j)*H + u] = f2bf(h);
          }
        }
      }
    }

    if (isOut) {                                  // linear head, pipelined at t = p-3
      const int to = p - 3;
      if (to >= 0 && to < Tt) {
        const unsigned short* hA = h3r + (size_t)(to&3)*Bb*Hb;
        floatx4 oacc[2][2];
        if (ki == 0) {
          #pragma unroll
          for (int nt = 0; nt < 2; ++nt) {
            float bv = biasl[osec + nt*16 + l15];
            floatx4 b4 = {bv, bv, bv, bv};
            oacc[0][nt] = b4; oacc[1][nt] = b4;
          }
        } else {
          floatx4 z = {0.f, 0.f, 0.f, 0.f};
          oacc[0][0] = z; oacc[0][1] = z; oacc[1][0] = z; oacc[1][1] = z;
        }
        for (int ks = 0; ks < 16; ++ks) {
          const int k = ki*512 + (ks << 5);
          short8 a[2], b[2];
          #pragma unroll
          for (int mt = 0; mt < 2; ++mt) {
            const int row = obase + mi*32 + mt*16 + l15;
            a[mt] = *(const short8*)(hA + (size_t)row*Hb + k + klo);
          }
          #pragma unroll
          for (int nt = 0; nt < 2; ++nt) {
            const int R = osec + nt*16 + l15;
            b[nt] = *(const short8*)(WL + (size_t)R*Hb + k + klo);
          }
          #pragma unroll
          for (int mt = 0; mt < 2; ++mt)
            #pragma unroll
            for (int nt = 0; nt < 2; ++nt)
              oacc[mt][nt] = __builtin_amdgcn_mfma_f32_16x16x32_bf16(a[mt], b[nt], oacc[mt][nt], 0, 0, 0);
        }
        __syncthreads();
        if (ki == 1) {
          #pragma unroll
          for (int mt = 0; mt < 2; ++mt)
            #pragma unroll
            for (int nt = 0; nt < 2; ++nt)
              red[(mi*8 + mt*2 + nt)*64 + lane] = oacc[mt][nt];
        }
        __syncthreads();
        if (ki == 0) {
          #pragma unroll
          for (int mt = 0; mt < 2; ++mt) {
            const int b0 = obase + mi*32 + mt*16 + ((lane >> 4) << 2);
            #pragma unroll
            for (int nt = 0; nt < 2; ++nt) {
              floatx4 v = oacc[mt][nt] + red[(mi*8 + mt*2 + nt)*64 + lane];
              const int col = osec + nt*16 + l15;
              #pragma unroll
              for (int j = 0; j < 4; ++j)
                out[((size_t)to*Bb + b0 + j)*Dl + col] = v[j];
            }
          }
        }
      }
    }

    // ---- grid barrier (release on arrive, relaxed spin, single acquire) ----
    if (p < NPHASE - 1) {
      __syncthreads();
      if (tid == 0) {
        __hip_atomic_fetch_add(cnt, 1u, __ATOMIC_RELEASE, __HIP_MEMORY_SCOPE_AGENT);
        const unsigned int tgt = (unsigned int)NWG*(unsigned int)(p + 1);
        while (__hip_atomic_load(cnt, __ATOMIC_RELAXED, __HIP_MEMORY_SCOPE_AGENT) < tgt)
          __builtin_amdgcn_s_sleep(2);
        (void)__hip_atomic_load(cnt, __ATOMIC_ACQUIRE, __HIP_MEMORY_SCOPE_AGENT);
      }
      __syncthreads();
    }
  }
}

extern "C" void kernel_launch(void* const* d_in, const int* in_sizes, int n_in,
                              void* d_out, int out_size, void* d_ws, size_t ws_size,
                              hipStream_t stream)
{
  if (ws_size < WS_NEED) return;  // would corrupt otherwise; fail loudly via poison output

  const float* X    = (const float*)d_in[0];
  const float* Wih1 = (const float*)d_in[1];
  const float* Whh1 = (const float*)d_in[2];
  const float* bih1 = (const float*)d_in[3];
  const float* bhh1 = (const float*)d_in[4];
  const float* Wih2 = (const float*)d_in[5];
  const float* Whh2 = (const float*)d_in[6];
  const float* bih2 = (const float*)d_in[7];
  const float* bhh2 = (const float*)d_in[8];
  const float* Wih3 = (const float*)d_in[9];
  const float* Whh3 = (const float*)d_in[10];
  const float* bih3 = (const float*)d_in[11];
  const float* bhh3 = (const float*)d_in[12];
  const float* Wlin = (const float*)d_in[13];
  const float* blin = (const float*)d_in[14];
  unsigned char* ws = (unsigned char*)d_ws;

  lstm_init<<<2048, 256, 0, stream>>>(Wih1, Whh1, bih1, bhh1,
                                      Wih2, Whh2, bih2, bhh2,
                                      Wih3, Whh3, bih3, bhh3,
                                      Wlin, blin, ws);
  lstm_persist<<<NWG, 256, 147456, stream>>>(X, (float*)d_out, ws);
}

// Round 2
// 6380.393 us; speedup vs baseline: 1.1432x; 1.1432x over previous
//
#include <hip/hip_runtime.h>
#include <stdint.h>

#define NWG 256
#define NPHASE 260   // T + 4 pipeline stages

typedef __attribute__((ext_vector_type(8))) short short8;
typedef __attribute__((ext_vector_type(4))) float floatx4;

static constexpr int Bb = 128, Tt = 256, Dl = 256, Hs = 512, Hb = 1024;

// ---- workspace byte layout ----
static constexpr size_t OFF_FLAGS = 0;                                   // u32[256]
static constexpr size_t OFF_B1  = 1024;                                  // f32[2048]
static constexpr size_t OFF_B2  = OFF_B1 + 2048*4;
static constexpr size_t OFF_B3  = OFF_B2 + 2048*4;                       // f32[4096]
static constexpr size_t OFF_BL  = OFF_B3 + 4096*4;                       // f32[256]
static constexpr size_t OFF_W1  = OFF_BL + 1024;                         // bf16[2048][768]
static constexpr size_t OFF_W2  = OFF_W1 + (size_t)2048*768*2;           // bf16[2048][1024]
static constexpr size_t OFF_W3  = OFF_W2 + (size_t)2048*1024*2;          // bf16[4096][1536]
static constexpr size_t OFF_WL  = OFF_W3 + (size_t)4096*1536*2;          // bf16[256][1024]
static constexpr size_t OFF_H1  = OFF_WL + (size_t)256*1024*2;           // bf16[4][128][512]
static constexpr size_t OFF_H2  = OFF_H1 + (size_t)4*128*512*2;
static constexpr size_t OFF_H3  = OFF_H2 + (size_t)4*128*512*2;          // bf16[4][128][1024]
static constexpr size_t OFF_XB  = OFF_H3 + (size_t)4*128*1024*2;         // bf16[2][128][256]
static constexpr size_t WS_NEED = OFF_XB + (size_t)2*128*256*2;          // ~22.8 MB

__device__ __forceinline__ unsigned short f2bf(float f) {
  unsigned int u = __float_as_uint(f);
  unsigned int r = (u + 0x7fffu + ((u >> 16) & 1u)) >> 16;
  return (unsigned short)r;
}
__device__ __forceinline__ float sigm(float x) { return 1.f/(1.f + __expf(-x)); }
__device__ __forceinline__ float tanh_f(float x) {
  x = fminf(fmaxf(x, -15.f), 15.f);
  float e = __expf(-2.f*x);
  return (1.f - e)/(1.f + e);
}

// LLC-coherent access helpers: cross-WG data never lives in (non-coherent) L2.
__device__ __forceinline__ short8 ldh16(const unsigned short* p) {
  unsigned long long* q = (unsigned long long*)p;
  union { unsigned long long u[2]; short8 s; } cv;
  cv.u[0] = __hip_atomic_load(q,     __ATOMIC_RELAXED, __HIP_MEMORY_SCOPE_AGENT);
  cv.u[1] = __hip_atomic_load(q + 1, __ATOMIC_RELAXED, __HIP_MEMORY_SCOPE_AGENT);
  return cv.s;
}
__device__ __forceinline__ void st_short_cg(unsigned short* p, unsigned int v) {
  asm volatile("global_store_short %0, %1, off sc0 sc1" :: "v"(p), "v"(v) : "memory");
}
__device__ __forceinline__ void st_dword_cg(void* p, unsigned int v) {
  asm volatile("global_store_dword %0, %1, off sc0 sc1" :: "v"(p), "v"(v) : "memory");
}
__device__ __forceinline__ void waitcnt_vm0() {
  asm volatile("s_waitcnt vmcnt(0)" ::: "memory");
}

// ---------------- init ----------------
__global__ void lstm_init(
    const float* __restrict__ Wih1, const float* __restrict__ Whh1,
    const float* __restrict__ bih1, const float* __restrict__ bhh1,
    const float* __restrict__ Wih2, const float* __restrict__ Whh2,
    const float* __restrict__ bih2, const float* __restrict__ bhh2,
    const float* __restrict__ Wih3, const float* __restrict__ Whh3,
    const float* __restrict__ bih3, const float* __restrict__ bhh3,
    const float* __restrict__ Wlin, const float* __restrict__ blin,
    unsigned char* __restrict__ ws)
{
  size_t i0 = (size_t)blockIdx.x*blockDim.x + threadIdx.x;
  size_t np = (size_t)gridDim.x*blockDim.x;

  unsigned int* fl = (unsigned int*)(ws + OFF_FLAGS);
  for (size_t i = i0; i < 256; i += np) fl[i] = 0u;

  float* b1 = (float*)(ws + OFF_B1);
  float* b2 = (float*)(ws + OFF_B2);
  float* b3 = (float*)(ws + OFF_B3);
  float* bl = (float*)(ws + OFF_BL);
  for (size_t i = i0; i < 2048; i += np) b1[i] = bih1[i] + bhh1[i];
  for (size_t i = i0; i < 2048; i += np) b2[i] = bih2[i] + bhh2[i];
  for (size_t i = i0; i < 4096; i += np) b3[i] = bih3[i] + bhh3[i];
  for (size_t i = i0; i < 256;  i += np) bl[i] = blin[i];

  unsigned short* w1 = (unsigned short*)(ws + OFF_W1);
  unsigned short* w2 = (unsigned short*)(ws + OFF_W2);
  unsigned short* w3 = (unsigned short*)(ws + OFF_W3);
  unsigned short* wl = (unsigned short*)(ws + OFF_WL);
  for (size_t i = i0; i < (size_t)2048*768; i += np) {
    size_t r = i/768, k = i - r*768;
    float v = (k < 256) ? Wih1[r*256 + k] : Whh1[r*512 + (k - 256)];
    w1[i] = f2bf(v);
  }
  for (size_t i = i0; i < (size_t)2048*1024; i += np) {
    size_t r = i >> 10, k = i & 1023;
    float v = (k < 512) ? Wih2[r*512 + k] : Whh2[r*512 + (k - 512)];
    w2[i] = f2bf(v);
  }
  for (size_t i = i0; i < (size_t)4096*1536; i += np) {
    size_t r = i/1536, k = i - r*1536;
    float v = (k < 512) ? Wih3[r*512 + k] : Whh3[r*1024 + (k - 512)];
    w3[i] = f2bf(v);
  }
  for (size_t i = i0; i < (size_t)256*1024; i += np) wl[i] = f2bf(Wlin[i]);

  unsigned short* rings = (unsigned short*)(ws + OFF_H1);
  for (size_t i = i0; i < (size_t)(4*128*512 + 4*128*512 + 4*128*1024); i += np) rings[i] = 0;
  unsigned short* xb = (unsigned short*)(ws + OFF_XB);
  for (size_t i = i0; i < (size_t)2*128*256; i += np) xb[i] = 0;
}

// ---------------- templated fully-unrolled K-loop (full load prefetch) ----------------
// TYPE0: x(bf16 staged, pitch 256)|h1 ; TYPE1: h1|h2 ; TYPE2: h2|h3 (+W tail from L2)
template<int TYPE, int KI>
__device__ __forceinline__ void layer_core(
    const unsigned short* __restrict__ segA,
    const unsigned short* __restrict__ segB,
    const unsigned short* __restrict__ Wg,   // full weight row-major, for TYPE2 global tail
    const unsigned char* smem,
    int u0, int rowbase, int l15, int klo,
    floatx4 acc[2][4])
{
  constexpr int KSN  = (TYPE==0 ? 12 : TYPE==1 ? 16 : 24);
  constexpr int KB1  = (TYPE==0 ? 256 : 512);
  constexpr int PA   = (TYPE==0 ? 256 : 512);
  constexpr int PB   = (TYPE==2 ? 1024 : 512);
  constexpr int KRES = (TYPE==1 ? 1024 : 768);
  constexpr int KF   = (TYPE==0 ? 768 : TYPE==1 ? 1024 : 1536);
  constexpr int K0   = KI * KSN * 32;

  short8 A[KSN][2];
  #pragma unroll
  for (int ks = 0; ks < KSN; ++ks) {
    const int kb = K0 + ks*32;          // segment choice independent of klo (kb mult of 32)
    #pragma unroll
    for (int mt = 0; mt < 2; ++mt) {
      const int row = rowbase + mt*16 + l15;
      const unsigned short* p = (kb < KB1)
          ? segA + (size_t)row*PA + kb + klo
          : segB + (size_t)row*PB + (kb - KB1) + klo;
      A[ks][mt] = ldh16(p);
    }
  }
  #pragma unroll
  for (int ks = 0; ks < KSN; ++ks) {
    const int kb = K0 + ks*32;
    short8 bf[4];
    #pragma unroll
    for (int g = 0; g < 4; ++g) {
      if (kb < KRES) {
        const int r  = (g << 4) + l15;
        const int db = r*(KRES*2) + (((kb + klo)*2) ^ ((r & 7) << 4));
        bf[g] = *(const short8*)(smem + db);
      } else {                           // TYPE2 second K-half straight from L2 (plain, cached)
        bf[g] = *(const short8*)(Wg + (size_t)(g*1024 + u0 + l15)*KF + kb + klo);
      }
    }
    #pragma unroll
    for (int mt = 0; mt < 2; ++mt)
      #pragma unroll
      for (int g = 0; g < 4; ++g)
        acc[mt][g] = __builtin_amdgcn_mfma_f32_16x16x32_bf16(A[ks][mt], bf[g], acc[mt][g], 0, 0, 0);
  }
}

// ---------------- persistent pipelined LSTM kernel ----------------
// phase p: L1 t=p-1 | L2 t=p-2 (+x-convert t=p) | L3 t=p-3 | head t=p-4
__global__ void __launch_bounds__(256, 1)
lstm_persist(const float* __restrict__ X, float* __restrict__ out,
             unsigned char* __restrict__ ws)
{
  extern __shared__ unsigned char smem[];            // [0,128K): weights, [128K,+16K): reduce
  floatx4* red = (floatx4*)(smem + 131072);

  const int tid  = threadIdx.x;
  const int lane = tid & 63;
  const int wv   = tid >> 6;
  const int mi   = wv & 1;
  const int ki   = wv >> 1;
  const int wg   = blockIdx.x;
  const int l15  = lane & 15;
  const int klo  = (lane >> 4) << 3;

  unsigned int* flags = (unsigned int*)(ws + OFF_FLAGS);
  const float* bias1 = (const float*)(ws + OFF_B1);
  const float* bias2 = (const float*)(ws + OFF_B2);
  const float* bias3 = (const float*)(ws + OFF_B3);
  const float* biasl = (const float*)(ws + OFF_BL);
  const unsigned short* W1 = (const unsigned short*)(ws + OFF_W1);
  const unsigned short* W2 = (const unsigned short*)(ws + OFF_W2);
  const unsigned short* W3 = (const unsigned short*)(ws + OFF_W3);
  const unsigned short* WL = (const unsigned short*)(ws + OFF_WL);
  unsigned short* h1r = (unsigned short*)(ws + OFF_H1);
  unsigned short* h2r = (unsigned short*)(ws + OFF_H2);
  unsigned short* h3r = (unsigned short*)(ws + OFF_H3);
  unsigned short* Xb  = (unsigned short*)(ws + OFF_XB);

  int type, mbase, u0, H, Kfull, Kres;
  const unsigned short* Wg; const float* biasp;
  if (wg < 64)       { type = 0; int j = wg;       mbase = (j&1)*64; u0 = (j>>1)*16; Wg = W1; biasp = bias1; H = Hs; Kfull = 768;  Kres = 768;  }
  else if (wg < 128) { type = 1; int j = wg - 64;  mbase = (j&1)*64; u0 = (j>>1)*16; Wg = W2; biasp = bias2; H = Hs; Kfull = 1024; Kres = 1024; }
  else               { type = 2; int j = wg - 128; mbase = (j&1)*64; u0 = (j>>1)*16; Wg = W3; biasp = bias3; H = Hb; Kfull = 1536; Kres = 768;  }
  const int rowbase = mbase + mi*32;

  const bool isOut = (wg < 64) && !(wg & 1);
  const int  ojob  = wg >> 1;            // 0..31
  const int  obase = (ojob & 1)*64;
  const int  osec  = (ojob >> 1)*16;

  // prologue: weight slice -> LDS (rows = 4 gates x 16 units, cols = Kres, XOR-swizzled)
  {
    const int rowchunks = Kres >> 3;
    for (int idx = tid; idx < 64*rowchunks; idx += 256) {
      int r = idx / rowchunks, kc = idx - r*rowchunks;
      int R = (r >> 4)*H + u0 + (r & 15);
      uint4 v = *(const uint4*)(Wg + (size_t)R*Kfull + kc*8);
      int db = r*(Kres*2) + ((kc*16) ^ ((r & 7) << 4));
      *(uint4*)(smem + db) = v;
    }
  }
  float creg[8];
  #pragma unroll
  for (int i = 0; i < 8; ++i) creg[i] = 0.f;

  __syncthreads();

  for (int p = 0; p < NPHASE; ++p) {
    const int t = p - 1 - type;
    if (t >= 0 && t < Tt) {
      const unsigned short *segA, *segB;
      if (type == 0)      { segA = Xb  + (size_t)(t&1)*Bb*Dl;      segB = h1r + (size_t)((t-1)&3)*Bb*Hs; }
      else if (type == 1) { segA = h1r + (size_t)(t&3)*Bb*Hs;      segB = h2r + (size_t)((t-1)&3)*Bb*Hs; }
      else                { segA = h2r + (size_t)(t&3)*Bb*Hs;      segB = h3r + (size_t)((t-1)&3)*Bb*Hb; }

      floatx4 acc[2][4];
      if (ki == 0) {
        #pragma unroll
        for (int g = 0; g < 4; ++g) {
          float bv = biasp[g*H + u0 + l15];
          floatx4 b4 = {bv, bv, bv, bv};
          acc[0][g] = b4; acc[1][g] = b4;
        }
      } else {
        floatx4 z = {0.f, 0.f, 0.f, 0.f};
        #pragma unroll
        for (int g = 0; g < 4; ++g) { acc[0][g] = z; acc[1][g] = z; }
      }

      if (type == 0) { if (ki == 0) layer_core<0,0>(segA, segB, Wg, smem, u0, rowbase, l15, klo, acc);
                       else         layer_core<0,1>(segA, segB, Wg, smem, u0, rowbase, l15, klo, acc); }
      else if (type == 1) { if (ki == 0) layer_core<1,0>(segA, segB, Wg, smem, u0, rowbase, l15, klo, acc);
                            else         layer_core<1,1>(segA, segB, Wg, smem, u0, rowbase, l15, klo, acc); }
      else { if (ki == 0) layer_core<2,0>(segA, segB, Wg, smem, u0, rowbase, l15, klo, acc);
             else         layer_core<2,1>(segA, segB, Wg, smem, u0, rowbase, l15, klo, acc); }

      __syncthreads();
      if (ki == 1) {
        #pragma unroll
        for (int mt = 0; mt < 2; ++mt)
          #pragma unroll
          for (int g = 0; g < 4; ++g)
            red[(mi*8 + mt*4 + g)*64 + lane] = acc[mt][g];
      }
      __syncthreads();
      if (ki == 0) {
        unsigned short* hout = (type == 0 ? h1r : type == 1 ? h2r : h3r) + (size_t)(t&3)*Bb*H;
        #pragma unroll
        for (int mt = 0; mt < 2; ++mt) {
          floatx4 gi = acc[mt][0] + red[(mi*8 + mt*4 + 0)*64 + lane];
          floatx4 gf = acc[mt][1] + red[(mi*8 + mt*4 + 1)*64 + lane];
          floatx4 gg = acc[mt][2] + red[(mi*8 + mt*4 + 2)*64 + lane];
          floatx4 go = acc[mt][3] + red[(mi*8 + mt*4 + 3)*64 + lane];
          const int b0 = rowbase + mt*16 + ((lane >> 4) << 2);
          const int u  = u0 + l15;
          #pragma unroll
          for (int j = 0; j < 4; ++j) {
            float iv = sigm(gi[j]);
            float fv = sigm(gf[j]);
            float gv = tanh_f(gg[j]);
            float ov = sigm(go[j]);
            float c  = fv*creg[mt*4 + j] + iv*gv;
            creg[mt*4 + j] = c;
            float h = ov*tanh_f(c);
            st_short_cg(hout + (size_t)(b0 + j)*H + u, (unsigned int)f2bf(h));
          }
        }
        waitcnt_vm0();
      }
    }

    if (isOut) {                                  // linear head, t = p-4, m64 x n16 per WG
      const int to = p - 4;
      if (to >= 0 && to < Tt) {
        const unsigned short* hA = h3r + (size_t)(to&3)*Bb*Hb;
        floatx4 oacc[2];
        if (ki == 0) {
          float bv = biasl[osec + l15];
          floatx4 b4 = {bv, bv, bv, bv};
          oacc[0] = b4; oacc[1] = b4;
        } else {
          floatx4 z = {0.f, 0.f, 0.f, 0.f};
          oacc[0] = z; oacc[1] = z;
        }
        short8 Ah[16][2];
        #pragma unroll
        for (int ks = 0; ks < 16; ++ks) {
          const int k = ki*512 + ks*32 + klo;
          #pragma unroll
          for (int mt = 0; mt < 2; ++mt) {
            const int row = obase + mi*32 + mt*16 + l15;
            Ah[ks][mt] = ldh16(hA + (size_t)row*Hb + k);
          }
        }
        #pragma unroll
        for (int ks = 0; ks < 16; ++ks) {
          const int k = ki*512 + ks*32 + klo;
          short8 bw = *(const short8*)(WL + (size_t)(osec + l15)*Hb + k);
          #pragma unroll
          for (int mt = 0; mt < 2; ++mt)
            oacc[mt] = __builtin_amdgcn_mfma_f32_16x16x32_bf16(Ah[ks][mt], bw, oacc[mt], 0, 0, 0);
        }
        __syncthreads();
        if (ki == 1) {
          red[(mi*2 + 0)*64 + lane] = oacc[0];
          red[(mi*2 + 1)*64 + lane] = oacc[1];
        }
        __syncthreads();
        if (ki == 0) {
          #pragma unroll
          for (int mt = 0; mt < 2; ++mt) {
            floatx4 v = oacc[mt] + red[(mi*2 + mt)*64 + lane];
            const int b0 = obase + mi*32 + mt*16 + ((lane >> 4) << 2);
            const int col = osec + l15;
            #pragma unroll
            for (int j = 0; j < 4; ++j)
              out[((size_t)to*Bb + b0 + j)*Dl + col] = v[j];
          }
        }
      }
    }

    if (type == 1 && p < Tt) {                    // stage x_{t=p} as bf16 for layer1 next phase
      const int j = wg - 64;
      const int i = tid*2;
      const int row = j*2 + (i >> 8);
      const int d = i & 255;
      const float* xp = X + ((size_t)row*Tt + p)*Dl + d;
      float2 v = *(const float2*)xp;
      unsigned int pk = (unsigned int)f2bf(v.x) | ((unsigned int)f2bf(v.y) << 16);
      st_dword_cg(Xb + (size_t)(p&1)*Bb*Dl + (size_t)row*Dl + d, pk);
      waitcnt_vm0();
    }

    // ---- grid barrier: per-WG coherent flag + all-threads direct poll ----
    if (p < NPHASE - 1) {
      __syncthreads();
      const unsigned int tgt = (unsigned int)(p + 1);
      if (tid == 0) {
        waitcnt_vm0();
        st_dword_cg(flags + wg, tgt);
      }
      while (__hip_atomic_load(flags + tid, __ATOMIC_RELAXED, __HIP_MEMORY_SCOPE_AGENT) < tgt)
        __builtin_amdgcn_s_sleep(1);
      asm volatile("" ::: "memory");
      __syncthreads();
    }
  }
}

extern "C" void kernel_launch(void* const* d_in, const int* in_sizes, int n_in,
                              void* d_out, int out_size, void* d_ws, size_t ws_size,
                              hipStream_t stream)
{
  if (ws_size < WS_NEED) return;

  const float* X    = (const float*)d_in[0];
  const float* Wih1 = (const float*)d_in[1];
  const float* Whh1 = (const float*)d_in[2];
  const float* bih1 = (const float*)d_in[3];
  const float* bhh1 = (const float*)d_in[4];
  const float* Wih2 = (const float*)d_in[5];
  const float* Whh2 = (const float*)d_in[6];
  const float* bih2 = (const float*)d_in[7];
  const float* bhh2 = (const float*)d_in[8];
  const float* Wih3 = (const float*)d_in[9];
  const float* Whh3 = (const float*)d_in[10];
  const float* bih3 = (const float*)d_in[11];
  const float* bhh3 = (const float*)d_in[12];
  const float* Wlin = (const float*)d_in[13];
  const float* blin = (const float*)d_in[14];
  unsigned char* ws = (unsigned char*)d_ws;

  lstm_init<<<2048, 256, 0, stream>>>(Wih1, Whh1, bih1, bhh1,
                                      Wih2, Whh2, bih2, bhh2,
                                      Wih3, Whh3, bih3, bhh3,
                                      Wlin, blin, ws);
  lstm_persist<<<NWG, 256, 147456, stream>>>(X, (float*)d_out, ws);
}

// Round 3
// 4801.222 us; speedup vs baseline: 1.5192x; 1.3289x over previous
//
#include <hip/hip_runtime.h>
#include <stdint.h>

#define NWG 256
#define NPHASE 260   // T + 4 pipeline stages

typedef __attribute__((ext_vector_type(8))) short short8;
typedef __attribute__((ext_vector_type(4))) float floatx4;

static constexpr int Bb = 128, Tt = 256, Dl = 256, Hs = 512, Hb = 1024;

// ---- workspace byte layout ----
static constexpr size_t OFF_FLAGS = 0;                                   // u32[256]
static constexpr size_t OFF_B1  = 1024;                                  // f32[2048]
static constexpr size_t OFF_B2  = OFF_B1 + 2048*4;
static constexpr size_t OFF_B3  = OFF_B2 + 2048*4;                       // f32[4096]
static constexpr size_t OFF_BL  = OFF_B3 + 4096*4;                       // f32[256]
static constexpr size_t OFF_W1  = OFF_BL + 1024;                         // bf16[2048][768]
static constexpr size_t OFF_W2  = OFF_W1 + (size_t)2048*768*2;           // bf16[2048][1024]
static constexpr size_t OFF_W3  = OFF_W2 + (size_t)2048*1024*2;          // bf16[4096][1536]
static constexpr size_t OFF_WL  = OFF_W3 + (size_t)4096*1536*2;          // bf16[256][1024]
static constexpr size_t OFF_H1  = OFF_WL + (size_t)256*1024*2;           // bf16[4][128][512]
static constexpr size_t OFF_H2  = OFF_H1 + (size_t)4*128*512*2;
static constexpr size_t OFF_H3  = OFF_H2 + (size_t)4*128*512*2;          // bf16[4][128][1024]
static constexpr size_t OFF_XB  = OFF_H3 + (size_t)4*128*1024*2;         // bf16[2][128][256]
static constexpr size_t WS_NEED = OFF_XB + (size_t)2*128*256*2;          // ~22.8 MB

__device__ __forceinline__ unsigned short f2bf(float f) {
  unsigned int u = __float_as_uint(f);
  unsigned int r = (u + 0x7fffu + ((u >> 16) & 1u)) >> 16;
  return (unsigned short)r;
}
__device__ __forceinline__ float sigm(float x) { return 1.f/(1.f + __expf(-x)); }
__device__ __forceinline__ float tanh_f(float x) {
  x = fminf(fmaxf(x, -15.f), 15.f);
  float e = __expf(-2.f*x);
  return (1.f - e)/(1.f + e);
}

// LLC-coherent plain vector load (issue only; caller must s_waitcnt before use!)
#define LDG16(dst, src) \
  asm volatile("global_load_dwordx4 %0, %1, off sc0 sc1" : "=v"(dst) : "v"(src))

__device__ __forceinline__ void st_short_cg(unsigned short* p, unsigned int v) {
  asm volatile("global_store_short %0, %1, off sc0 sc1" :: "v"(p), "v"(v) : "memory");
}
__device__ __forceinline__ void st_dword_cg(void* p, unsigned int v) {
  asm volatile("global_store_dword %0, %1, off sc0 sc1" :: "v"(p), "v"(v) : "memory");
}
__device__ __forceinline__ void waitcnt_vm0() {
  asm volatile("s_waitcnt vmcnt(0)" ::: "memory");
}

// ---------------- init ----------------
__global__ void lstm_init(
    const float* __restrict__ Wih1, const float* __restrict__ Whh1,
    const float* __restrict__ bih1, const float* __restrict__ bhh1,
    const float* __restrict__ Wih2, const float* __restrict__ Whh2,
    const float* __restrict__ bih2, const float* __restrict__ bhh2,
    const float* __restrict__ Wih3, const float* __restrict__ Whh3,
    const float* __restrict__ bih3, const float* __restrict__ bhh3,
    const float* __restrict__ Wlin, const float* __restrict__ blin,
    unsigned char* __restrict__ ws)
{
  size_t i0 = (size_t)blockIdx.x*blockDim.x + threadIdx.x;
  size_t np = (size_t)gridDim.x*blockDim.x;

  unsigned int* fl = (unsigned int*)(ws + OFF_FLAGS);
  for (size_t i = i0; i < 256; i += np) fl[i] = 0u;

  float* b1 = (float*)(ws + OFF_B1);
  float* b2 = (float*)(ws + OFF_B2);
  float* b3 = (float*)(ws + OFF_B3);
  float* bl = (float*)(ws + OFF_BL);
  for (size_t i = i0; i < 2048; i += np) b1[i] = bih1[i] + bhh1[i];
  for (size_t i = i0; i < 2048; i += np) b2[i] = bih2[i] + bhh2[i];
  for (size_t i = i0; i < 4096; i += np) b3[i] = bih3[i] + bhh3[i];
  for (size_t i = i0; i < 256;  i += np) bl[i] = blin[i];

  unsigned short* w1 = (unsigned short*)(ws + OFF_W1);
  unsigned short* w2 = (unsigned short*)(ws + OFF_W2);
  unsigned short* w3 = (unsigned short*)(ws + OFF_W3);
  unsigned short* wl = (unsigned short*)(ws + OFF_WL);
  for (size_t i = i0; i < (size_t)2048*768; i += np) {
    size_t r = i/768, k = i - r*768;
    float v = (k < 256) ? Wih1[r*256 + k] : Whh1[r*512 + (k - 256)];
    w1[i] = f2bf(v);
  }
  for (size_t i = i0; i < (size_t)2048*1024; i += np) {
    size_t r = i >> 10, k = i & 1023;
    float v = (k < 512) ? Wih2[r*512 + k] : Whh2[r*512 + (k - 512)];
    w2[i] = f2bf(v);
  }
  for (size_t i = i0; i < (size_t)4096*1536; i += np) {
    size_t r = i/1536, k = i - r*1536;
    float v = (k < 512) ? Wih3[r*512 + k] : Whh3[r*1024 + (k - 512)];
    w3[i] = f2bf(v);
  }
  for (size_t i = i0; i < (size_t)256*1024; i += np) wl[i] = f2bf(Wlin[i]);

  unsigned short* rings = (unsigned short*)(ws + OFF_H1);
  for (size_t i = i0; i < (size_t)(4*128*512 + 4*128*512 + 4*128*1024); i += np) rings[i] = 0;
  unsigned short* xb = (unsigned short*)(ws + OFF_XB);
  for (size_t i = i0; i < (size_t)2*128*256; i += np) xb[i] = 0;
}

// ---------------- templated fully-unrolled K-loop (batched asm prefetch) ----------------
// TYPE0: x(bf16 staged, pitch 256)|h1 ; TYPE1: h1|h2 ; TYPE2: h2|h3 (+W tail from L2)
template<int TYPE, int KI>
__device__ __forceinline__ void layer_core(
    const unsigned short* __restrict__ segA,
    const unsigned short* __restrict__ segB,
    const unsigned short* __restrict__ Wg,   // full weight row-major, for TYPE2 global tail
    const unsigned char* smem,
    int u0, int rowbase, int l15, int klo,
    floatx4 acc[2][4])
{
  constexpr int KSN  = (TYPE==0 ? 12 : TYPE==1 ? 16 : 24);
  constexpr int KB1  = (TYPE==0 ? 256 : 512);
  constexpr int PA   = (TYPE==0 ? 256 : 512);
  constexpr int PB   = (TYPE==2 ? 1024 : 512);
  constexpr int KRES = (TYPE==1 ? 1024 : 768);
  constexpr int KF   = (TYPE==0 ? 768 : TYPE==1 ? 1024 : 1536);
  constexpr int K0   = KI * KSN * 32;

  // issue ALL A-loads as one batch of independent LLC loads
  short8 A[KSN][2];
  #pragma unroll
  for (int ks = 0; ks < KSN; ++ks) {
    const int kb = K0 + ks*32;          // segment choice independent of klo (kb mult of 32)
    #pragma unroll
    for (int mt = 0; mt < 2; ++mt) {
      const int row = rowbase + mt*16 + l15;
      const unsigned short* p = (kb < KB1)
          ? segA + (size_t)row*PA + kb + klo
          : segB + (size_t)row*PB + (kb - KB1) + klo;
      LDG16(A[ks][mt], p);
    }
  }
  asm volatile("s_waitcnt vmcnt(0)" ::: "memory");
  __builtin_amdgcn_sched_barrier(0);

  #pragma unroll
  for (int ks = 0; ks < KSN; ++ks) {
    const int kb = K0 + ks*32;
    short8 bf[4];
    #pragma unroll
    for (int g = 0; g < 4; ++g) {
      if (kb < KRES) {
        const int r  = (g << 4) + l15;
        const int db = r*(KRES*2) + (((kb + klo)*2) ^ ((r & 7) << 4));
        bf[g] = *(const short8*)(smem + db);
      } else {                           // TYPE2 second K-half straight from L2 (plain, cached)
        bf[g] = *(const short8*)(Wg + (size_t)(g*1024 + u0 + l15)*KF + kb + klo);
      }
    }
    #pragma unroll
    for (int mt = 0; mt < 2; ++mt)
      #pragma unroll
      for (int g = 0; g < 4; ++g)
        acc[mt][g] = __builtin_amdgcn_mfma_f32_16x16x32_bf16(A[ks][mt], bf[g], acc[mt][g], 0, 0, 0);
  }
}

// ---------------- persistent pipelined LSTM kernel ----------------
// phase p: L1 t=p-1 | L2 t=p-2 (+x-convert t=p) | L3 t=p-3 | head t=p-4
__global__ void __launch_bounds__(256, 1)
lstm_persist(const float* __restrict__ X, float* __restrict__ out,
             unsigned char* __restrict__ ws)
{
  extern __shared__ unsigned char smem[];            // [0,128K): weights, [128K,+16K): reduce
  floatx4* red = (floatx4*)(smem + 131072);

  const int tid  = threadIdx.x;
  const int lane = tid & 63;
  const int wv   = tid >> 6;
  const int mi   = wv & 1;
  const int ki   = wv >> 1;
  const int wg   = blockIdx.x;
  const int l15  = lane & 15;
  const int klo  = (lane >> 4) << 3;

  unsigned int* flags = (unsigned int*)(ws + OFF_FLAGS);
  const float* bias1 = (const float*)(ws + OFF_B1);
  const float* bias2 = (const float*)(ws + OFF_B2);
  const float* bias3 = (const float*)(ws + OFF_B3);
  const float* biasl = (const float*)(ws + OFF_BL);
  const unsigned short* W1 = (const unsigned short*)(ws + OFF_W1);
  const unsigned short* W2 = (const unsigned short*)(ws + OFF_W2);
  const unsigned short* W3 = (const unsigned short*)(ws + OFF_W3);
  const unsigned short* WL = (const unsigned short*)(ws + OFF_WL);
  unsigned short* h1r = (unsigned short*)(ws + OFF_H1);
  unsigned short* h2r = (unsigned short*)(ws + OFF_H2);
  unsigned short* h3r = (unsigned short*)(ws + OFF_H3);
  unsigned short* Xb  = (unsigned short*)(ws + OFF_XB);

  int type, mbase, u0, H, Kfull, Kres;
  const unsigned short* Wg; const float* biasp;
  if (wg < 64)       { type = 0; int j = wg;       mbase = (j&1)*64; u0 = (j>>1)*16; Wg = W1; biasp = bias1; H = Hs; Kfull = 768;  Kres = 768;  }
  else if (wg < 128) { type = 1; int j = wg - 64;  mbase = (j&1)*64; u0 = (j>>1)*16; Wg = W2; biasp = bias2; H = Hs; Kfull = 1024; Kres = 1024; }
  else               { type = 2; int j = wg - 128; mbase = (j&1)*64; u0 = (j>>1)*16; Wg = W3; biasp = bias3; H = Hb; Kfull = 1536; Kres = 768;  }
  const int rowbase = mbase + mi*32;

  const bool isOut = (wg < 64) && !(wg & 1);
  const int  ojob  = wg >> 1;            // 0..31
  const int  obase = (ojob & 1)*64;
  const int  osec  = (ojob >> 1)*16;

  // prologue: weight slice -> LDS (rows = 4 gates x 16 units, cols = Kres, XOR-swizzled)
  {
    const int rowchunks = Kres >> 3;
    for (int idx = tid; idx < 64*rowchunks; idx += 256) {
      int r = idx / rowchunks, kc = idx - r*rowchunks;
      int R = (r >> 4)*H + u0 + (r & 15);
      uint4 v = *(const uint4*)(Wg + (size_t)R*Kfull + kc*8);
      int db = r*(Kres*2) + ((kc*16) ^ ((r & 7) << 4));
      *(uint4*)(smem + db) = v;
    }
  }
  float creg[8];
  #pragma unroll
  for (int i = 0; i < 8; ++i) creg[i] = 0.f;

  __syncthreads();

  for (int p = 0; p < NPHASE; ++p) {
    const int t = p - 1 - type;
    if (t >= 0 && t < Tt) {
      const unsigned short *segA, *segB;
      if (type == 0)      { segA = Xb  + (size_t)(t&1)*Bb*Dl;      segB = h1r + (size_t)((t-1)&3)*Bb*Hs; }
      else if (type == 1) { segA = h1r + (size_t)(t&3)*Bb*Hs;      segB = h2r + (size_t)((t-1)&3)*Bb*Hs; }
      else                { segA = h2r + (size_t)(t&3)*Bb*Hs;      segB = h3r + (size_t)((t-1)&3)*Bb*Hb; }

      floatx4 acc[2][4];
      if (ki == 0) {
        #pragma unroll
        for (int g = 0; g < 4; ++g) {
          float bv = biasp[g*H + u0 + l15];
          floatx4 b4 = {bv, bv, bv, bv};
          acc[0][g] = b4; acc[1][g] = b4;
        }
      } else {
        floatx4 z = {0.f, 0.f, 0.f, 0.f};
        #pragma unroll
        for (int g = 0; g < 4; ++g) { acc[0][g] = z; acc[1][g] = z; }
      }

      if (type == 0) { if (ki == 0) layer_core<0,0>(segA, segB, Wg, smem, u0, rowbase, l15, klo, acc);
                       else         layer_core<0,1>(segA, segB, Wg, smem, u0, rowbase, l15, klo, acc); }
      else if (type == 1) { if (ki == 0) layer_core<1,0>(segA, segB, Wg, smem, u0, rowbase, l15, klo, acc);
                            else         layer_core<1,1>(segA, segB, Wg, smem, u0, rowbase, l15, klo, acc); }
      else { if (ki == 0) layer_core<2,0>(segA, segB, Wg, smem, u0, rowbase, l15, klo, acc);
             else         layer_core<2,1>(segA, segB, Wg, smem, u0, rowbase, l15, klo, acc); }

      __syncthreads();
      if (ki == 1) {
        #pragma unroll
        for (int mt = 0; mt < 2; ++mt)
          #pragma unroll
          for (int g = 0; g < 4; ++g)
            red[(mi*8 + mt*4 + g)*64 + lane] = acc[mt][g];
      }
      __syncthreads();
      if (ki == 0) {
        unsigned short* hout = (type == 0 ? h1r : type == 1 ? h2r : h3r) + (size_t)(t&3)*Bb*H;
        #pragma unroll
        for (int mt = 0; mt < 2; ++mt) {
          floatx4 gi = acc[mt][0] + red[(mi*8 + mt*4 + 0)*64 + lane];
          floatx4 gf = acc[mt][1] + red[(mi*8 + mt*4 + 1)*64 + lane];
          floatx4 gg = acc[mt][2] + red[(mi*8 + mt*4 + 2)*64 + lane];
          floatx4 go = acc[mt][3] + red[(mi*8 + mt*4 + 3)*64 + lane];
          const int b0 = rowbase + mt*16 + ((lane >> 4) << 2);
          const int u  = u0 + l15;
          #pragma unroll
          for (int j = 0; j < 4; ++j) {
            float iv = sigm(gi[j]);
            float fv = sigm(gf[j]);
            float gv = tanh_f(gg[j]);
            float ov = sigm(go[j]);
            float c  = fv*creg[mt*4 + j] + iv*gv;
            creg[mt*4 + j] = c;
            float h = ov*tanh_f(c);
            st_short_cg(hout + (size_t)(b0 + j)*H + u, (unsigned int)f2bf(h));
          }
        }
        waitcnt_vm0();
      }
    }

    if (isOut) {                                  // linear head, t = p-4, m64 x n16 per WG
      const int to = p - 4;
      if (to >= 0 && to < Tt) {
        const unsigned short* hA = h3r + (size_t)(to&3)*Bb*Hb;
        floatx4 oacc[2];
        if (ki == 0) {
          float bv = biasl[osec + l15];
          floatx4 b4 = {bv, bv, bv, bv};
          oacc[0] = b4; oacc[1] = b4;
        } else {
          floatx4 z = {0.f, 0.f, 0.f, 0.f};
          oacc[0] = z; oacc[1] = z;
        }
        short8 Ah[16][2];
        #pragma unroll
        for (int ks = 0; ks < 16; ++ks) {
          const int k = ki*512 + ks*32 + klo;
          #pragma unroll
          for (int mt = 0; mt < 2; ++mt) {
            const int row = obase + mi*32 + mt*16 + l15;
            LDG16(Ah[ks][mt], hA + (size_t)row*Hb + k);
          }
        }
        asm volatile("s_waitcnt vmcnt(0)" ::: "memory");
        __builtin_amdgcn_sched_barrier(0);
        #pragma unroll
        for (int ks = 0; ks < 16; ++ks) {
          const int k = ki*512 + ks*32 + klo;
          short8 bw = *(const short8*)(WL + (size_t)(osec + l15)*Hb + k);
          #pragma unroll
          for (int mt = 0; mt < 2; ++mt)
            oacc[mt] = __builtin_amdgcn_mfma_f32_16x16x32_bf16(Ah[ks][mt], bw, oacc[mt], 0, 0, 0);
        }
        __syncthreads();
        if (ki == 1) {
          red[(mi*2 + 0)*64 + lane] = oacc[0];
          red[(mi*2 + 1)*64 + lane] = oacc[1];
        }
        __syncthreads();
        if (ki == 0) {
          #pragma unroll
          for (int mt = 0; mt < 2; ++mt) {
            floatx4 v = oacc[mt] + red[(mi*2 + mt)*64 + lane];
            const int b0 = obase + mi*32 + mt*16 + ((lane >> 4) << 2);
            const int col = osec + l15;
            #pragma unroll
            for (int j = 0; j < 4; ++j)
              out[((size_t)to*Bb + b0 + j)*Dl + col] = v[j];
          }
        }
      }
    }

    if (type == 1 && p < Tt) {                    // stage x_{t=p} as bf16 for layer1 next phase
      const int j = wg - 64;
      const int i = tid*2;
      const int row = j*2 + (i >> 8);
      const int d = i & 255;
      const float* xp = X + ((size_t)row*Tt + p)*Dl + d;
      float2 v = *(const float2*)xp;
      unsigned int pk = (unsigned int)f2bf(v.x) | ((unsigned int)f2bf(v.y) << 16);
      st_dword_cg(Xb + (size_t)(p&1)*Bb*Dl + (size_t)row*Dl + d, pk);
      waitcnt_vm0();
    }

    // ---- grid barrier: per-WG coherent flag; only wave 0 polls ----
    if (p < NPHASE - 1) {
      __syncthreads();
      const unsigned int tgt = (unsigned int)(p + 1);
      if (tid == 0) {
        waitcnt_vm0();
        st_dword_cg(flags + wg, tgt);
      }
      if (tid < 64) {
        uint4 f;
        for (;;) {
          asm volatile("global_load_dwordx4 %0, %1, off sc0 sc1\n\t"
                       "s_waitcnt vmcnt(0)"
                       : "=v"(f) : "v"(flags + lane*4) : "memory");
          if (f.x >= tgt && f.y >= tgt && f.z >= tgt && f.w >= tgt) break;
          __builtin_amdgcn_s_sleep(2);
        }
      }
      __syncthreads();
    }
  }
}

extern "C" void kernel_launch(void* const* d_in, const int* in_sizes, int n_in,
                              void* d_out, int out_size, void* d_ws, size_t ws_size,
                              hipStream_t stream)
{
  if (ws_size < WS_NEED) return;

  const float* X    = (const float*)d_in[0];
  const float* Wih1 = (const float*)d_in[1];
  const float* Whh1 = (const float*)d_in[2];
  const float* bih1 = (const float*)d_in[3];
  const float* bhh1 = (const float*)d_in[4];
  const float* Wih2 = (const float*)d_in[5];
  const float* Whh2 = (const float*)d_in[6];
  const float* bih2 = (const float*)d_in[7];
  const float* bhh2 = (const float*)d_in[8];
  const float* Wih3 = (const float*)d_in[9];
  const float* Whh3 = (const float*)d_in[10];
  const float* bih3 = (const float*)d_in[11];
  const float* bhh3 = (const float*)d_in[12];
  const float* Wlin = (const float*)d_in[13];
  const float* blin = (const float*)d_in[14];
  unsigned char* ws = (unsigned char*)d_ws;

  lstm_init<<<2048, 256, 0, stream>>>(Wih1, Whh1, bih1, bhh1,
                                      Wih2, Whh2, bih2, bhh2,
                                      Wih3, Whh3, bih3, bhh3,
                                      Wlin, blin, ws);
  lstm_persist<<<NWG, 256, 147456, stream>>>(X, (float*)d_out, ws);
}